// Round 19
// baseline (24.255 us; speedup 1.0000x reference)
//
#include <hip/hip_runtime.h>

// TransformerBlockQuantum: B=16384, S=8, E=8, H=8 (dk=1), NW=8, FFN=512.
// R19: ILP-for-TLP — 2 tokens per thread. 256 blocks x 256 thr; thread owns
// tokens (blk*512+tid) and (+256): two INDEPENDENT front chains interleaved
// stage-by-stage (stall-filling without any cross-lane exchange overhead).
// kv f16-pack halves attention DS ops per token. Front weights in LDS (wl).
// FFN: wave owns 128 tokens = 8 MFMA tiles, 8 independent acc chains,
// fragments LDS-staged once per block (pack phase halved vs R17).
// launch_bounds(256,1): 4 waves/CU, VGPR-free.

typedef __fp16 half2v __attribute__((ext_vector_type(2)));
typedef __fp16 half4  __attribute__((ext_vector_type(4)));
typedef float  float4v __attribute__((ext_vector_type(4)));

#define SWZ16(v) __int_as_float(__builtin_amdgcn_ds_swizzle(__float_as_int(v), (16 << 10) | 0x1F))
#define SWZI_(v, dlit) __builtin_amdgcn_ds_swizzle((v), ((dlit) << 5) | 0x18)
#define DOT8(a, w0, w1)                                                   \
    fmaf((a)[7], (w1).w, fmaf((a)[6], (w1).z, fmaf((a)[5], (w1).y,        \
    fmaf((a)[4], (w1).x, fmaf((a)[3], (w0).w, fmaf((a)[2], (w0).z,        \
    fmaf((a)[1], (w0).y, (a)[0] * (w0).x)))))))

// float offsets in wl[]
#define O_IPW 0
#define O_OPW 192
#define O_CW  256
#define O_IPB 320
#define O_OPB 344
#define O_CB  352
#define O_RXA 360
#define O_G1  368
#define O_B1  376
#define O_RXF 384
#define O_L2B 392
#define O_G2  400
#define O_B2  408

__global__ __launch_bounds__(256, 1) void tbq_fused(
    const float* __restrict__ x,
    const float* __restrict__ ipw, const float* __restrict__ ipb,
    const float* __restrict__ opw, const float* __restrict__ opb,
    const float* __restrict__ rxa,
    const float* __restrict__ cw,  const float* __restrict__ cb,
    const float* __restrict__ g1,  const float* __restrict__ b1,
    const float* __restrict__ rxf,
    const float* __restrict__ l1w, const float* __restrict__ l1b,
    const float* __restrict__ l2w, const float* __restrict__ l2b,
    const float* __restrict__ g2,  const float* __restrict__ b2,
    float* __restrict__ out)
{
    __shared__ half4 a1l[2048];                       // 16KB
    __shared__ half4 a2l[2048];                       // 16KB
    __shared__ __align__(16) float lds_hh[512][12];   // 24KB
    __shared__ __align__(16) float wl[416];           // 1.6KB front weights

    const int tid = threadIdx.x;
    const int l   = tid & 63;
    const int wv  = tid >> 6;
    const int gbase = blockIdx.x * 512;               // block's first token

    // ---- issue both x loads first (HBM latency overlaps pack) ----
    float4 xa[2], xb[2];
    {
        const float4* p0 = reinterpret_cast<const float4*>(x + (gbase + tid) * 8);
        const float4* p1 = reinterpret_cast<const float4*>(x + (gbase + 256 + tid) * 8);
        xa[0] = p0[0]; xb[0] = p0[1];
        xa[1] = p1[0]; xb[1] = p1[1];
    }

    // ---- stage all front weights/biases into LDS ----
    if (tid < 192) wl[O_IPW + tid] = ipw[tid];
    else           wl[O_OPW + (tid - 192)] = opw[tid - 192];
    if (tid < 64)  wl[O_CW + tid] = cw[tid];
    if (tid < 24)  wl[O_IPB + tid] = ipb[tid];
    if (tid < 8) {
        wl[O_OPB + tid] = opb[tid]; wl[O_CB + tid]  = cb[tid];
        wl[O_RXA + tid] = rxa[tid]; wl[O_G1 + tid]  = g1[tid];
        wl[O_B1 + tid]  = b1[tid];  wl[O_RXF + tid] = rxf[tid];
        wl[O_L2B + tid] = l2b[tid]; wl[O_G2 + tid]  = g2[tid];
        wl[O_B2 + tid]  = b2[tid];
    }

    // ---- cooperative fragment pack: f32 weights -> f16 frags in LDS ----
    const half4 zh = {(__fp16)0.f, (__fp16)0.f, (__fp16)0.f, (__fp16)0.f};
    #pragma unroll 1
    for (int i = 0; i < 8; ++i) {
        const int u  = tid + i * 256;
        const int nf = u >> 6, ll = u & 63;
        const int mm = ll & 15, kk0 = (ll >> 4) * 4;
        half4 r1 = zh;
        if (ll < 32) {
            float4 w = *reinterpret_cast<const float4*>(l1w + (nf * 16 + mm) * 8 + kk0);
            half2v c0 = __builtin_amdgcn_cvt_pkrtz(w.x, w.y);
            half2v c1 = __builtin_amdgcn_cvt_pkrtz(w.z, w.w);
            r1.x = c0.x; r1.y = c0.y; r1.z = c1.x; r1.w = c1.y;
        } else if (ll < 48) {
            r1.x = (__fp16)l1b[nf * 16 + mm];
        }
        a1l[u] = r1;
        half4 r2 = zh;
        if (mm < 8) {
            float4 w = *reinterpret_cast<const float4*>(l2w + mm * 512 + nf * 16 + kk0);
            half2v c0 = __builtin_amdgcn_cvt_pkrtz(w.x, w.y);
            half2v c1 = __builtin_amdgcn_cvt_pkrtz(w.z, w.w);
            r2.x = c0.x; r2.y = c0.y; r2.z = c1.x; r2.w = c1.y;
        }
        a2l[u] = r2;
    }
    __syncthreads();   // weights + fragments visible to all

    const float4* wl4 = reinterpret_cast<const float4*>(wl);

    // ---- front: 2 independent chains per thread, stage-interleaved ----
    float xr[2][8];
    #pragma unroll
    for (int s = 0; s < 2; ++s) {
        xr[s][0] = xa[s].x; xr[s][1] = xa[s].y; xr[s][2] = xa[s].z; xr[s][3] = xa[s].w;
        xr[s][4] = xb[s].x; xr[s][5] = xb[s].y; xr[s][6] = xb[s].z; xr[s][7] = xb[s].w;
    }

    float q[2][8], k[2][8], v[2][8];
    #pragma unroll
    for (int e = 0; e < 8; ++e) {
        float4 wq0 = wl4[e * 2],      wq1 = wl4[e * 2 + 1];
        float4 wk0 = wl4[16 + e * 2], wk1 = wl4[16 + e * 2 + 1];
        float4 wv0 = wl4[32 + e * 2], wv1 = wl4[32 + e * 2 + 1];
        float bq = wl[O_IPB + e], bk = wl[O_IPB + 8 + e], bv = wl[O_IPB + 16 + e];
        #pragma unroll
        for (int s = 0; s < 2; ++s) {
            q[s][e] = bq + DOT8(xr[s], wq0, wq1);
            k[s][e] = bk + DOT8(xr[s], wk0, wk1);
            v[s][e] = bv + DOT8(xr[s], wv0, wv1);
        }
    }

    // attention: kv f16-packed, one swizzle per (s,h,j); no max-sub; exp2
    float orow[2][8];
    #pragma unroll
    for (int h = 0; h < 8; ++h) {
        #pragma unroll
        for (int s = 0; s < 2; ++s) {
            half2v pk = __builtin_amdgcn_cvt_pkrtz(k[s][h], v[s][h]);
            int kvp = __builtin_bit_cast(int, pk);
            int kvg[8];
            kvg[0] = SWZI_(kvp, 0); kvg[1] = SWZI_(kvp, 1);
            kvg[2] = SWZI_(kvp, 2); kvg[3] = SWZI_(kvp, 3);
            kvg[4] = SWZI_(kvp, 4); kvg[5] = SWZI_(kvp, 5);
            kvg[6] = SWZI_(kvp, 6); kvg[7] = SWZI_(kvp, 7);
            const float qh2 = q[s][h] * 1.44269504f;
            float sum = 0.f, ov = 0.f;
            #pragma unroll
            for (int j = 0; j < 8; ++j) {
                half2v kv = __builtin_bit_cast(half2v, kvg[j]);
                float p = exp2f(qh2 * (float)kv.x);
                sum += p;
                ov = fmaf(p, (float)kv.y, ov);
            }
            orow[s][h] = ov * __builtin_amdgcn_rcpf(sum);
        }
    }

    float ao[2][8];
    #pragma unroll
    for (int e = 0; e < 8; ++e) {
        float4 wo0 = wl4[48 + e * 2], wo1 = wl4[48 + e * 2 + 1];
        float bo = wl[O_OPB + e];
        #pragma unroll
        for (int s = 0; s < 2; ++s) ao[s][e] = bo + DOT8(orow[s], wo0, wo1);
    }

    float z[2][8];
    #pragma unroll
    for (int s = 0; s < 2; ++s) {
        float c[8];
        #pragma unroll
        for (int w = 0; w < 8; ++w) c[w] = __cosf(ao[s][w] + wl[O_RXA + w]);
        float run = c[0];
        #pragma unroll
        for (int w = 1; w < 8; ++w) { run *= c[w]; z[s][w] = run; }
        float s17 = c[1];
        #pragma unroll
        for (int w = 2; w < 8; ++w) s17 *= c[w];
        z[s][0] = s17;
    }

    float saq[2][8];
    #pragma unroll
    for (int e = 0; e < 8; ++e) {
        float4 wc0 = wl4[64 + e * 2], wc1 = wl4[64 + e * 2 + 1];
        float bc = wl[O_CB + e];
        #pragma unroll
        for (int s = 0; s < 2; ++s) saq[s][e] = ao[s][e] + bc + DOT8(z[s], wc0, wc1);
    }
    float at[2][8];
    #pragma unroll
    for (int e = 0; e < 8; ++e) {
        float4 wc0 = wl4[64 + e * 2], wc1 = wl4[64 + e * 2 + 1];
        float bc = wl[O_CB + e];
        #pragma unroll
        for (int s = 0; s < 2; ++s) at[s][e] = bc + DOT8(saq[s], wc0, wc1);
    }

    #pragma unroll
    for (int s = 0; s < 2; ++s) {
        float r[8]; float mean = 0.f;
        #pragma unroll
        for (int e = 0; e < 8; ++e) { r[e] = xr[s][e] + at[s][e]; mean += r[e]; }
        mean *= 0.125f;
        float var = 0.f;
        #pragma unroll
        for (int e = 0; e < 8; ++e) { float d = r[e] - mean; var = fmaf(d, d, var); }
        var *= 0.125f;
        float rs = __builtin_amdgcn_rsqf(var + 1e-5f);
        float4 hlo, hhi;
        hlo.x = fmaf((r[0] - mean) * rs, wl[O_G1 + 0], wl[O_B1 + 0]);
        hlo.y = fmaf((r[1] - mean) * rs, wl[O_G1 + 1], wl[O_B1 + 1]);
        hlo.z = fmaf((r[2] - mean) * rs, wl[O_G1 + 2], wl[O_B1 + 2]);
        hlo.w = fmaf((r[3] - mean) * rs, wl[O_G1 + 3], wl[O_B1 + 3]);
        hhi.x = fmaf((r[4] - mean) * rs, wl[O_G1 + 4], wl[O_B1 + 4]);
        hhi.y = fmaf((r[5] - mean) * rs, wl[O_G1 + 5], wl[O_B1 + 5]);
        hhi.z = fmaf((r[6] - mean) * rs, wl[O_G1 + 6], wl[O_B1 + 6]);
        hhi.w = fmaf((r[7] - mean) * rs, wl[O_G1 + 7], wl[O_B1 + 7]);
        *reinterpret_cast<float4*>(&lds_hh[tid + s * 256][0]) = hlo;
        *reinterpret_cast<float4*>(&lds_hh[tid + s * 256][4]) = hhi;
    }
    // No barrier: wave wv's FFN reads lds_hh rows wv*64..+63 and +256..+319,
    // all written by this same wave (lgkmcnt-ordered). Waves drift phase.

    // ---- FFN: wave owns 128 tokens = 8 tiles (A: wv*64+{0,16,32,48};
    //      B: 256+wv*64+{0,16,32,48}) ----
    const int m  = l & 15;
    const int kg = (l >> 4) * 4;
    const int wtok = wv * 64;

    half4 bz[8];
    #pragma unroll
    for (int tt = 0; tt < 8; ++tt) bz[tt] = zh;
    if (l < 32) {
        float4 rx4 = *reinterpret_cast<const float4*>(&wl[O_RXF + kg]);
        #pragma unroll
        for (int tt = 0; tt < 8; ++tt) {
            const int ltok = (tt & 4) * 64 + wtok + (tt & 3) * 16 + m;  // tt>=4 -> +256
            float4 h4 = *reinterpret_cast<const float4*>(&lds_hh[ltok][kg]);
            half2v c0 = __builtin_amdgcn_cvt_pkrtz(__cosf(h4.x + rx4.x), __cosf(h4.y + rx4.y));
            half2v c1 = __builtin_amdgcn_cvt_pkrtz(__cosf(h4.z + rx4.z), __cosf(h4.w + rx4.w));
            half4 b; b.x = c0.x; b.y = c0.y; b.z = c1.x; b.w = c1.y;
            bz[tt] = b;
        }
    } else if (l < 48) {
        #pragma unroll
        for (int tt = 0; tt < 8; ++tt) bz[tt].x = (__fp16)1.f;  // bias row k==8
    }

    const float4v zero4 = {0.f, 0.f, 0.f, 0.f};
    float4v acc[8];
    #pragma unroll
    for (int tt = 0; tt < 8; ++tt) acc[tt] = zero4;

    #pragma unroll 2
    for (int nf = 0; nf < 32; ++nf) {
        half4 a1f = a1l[nf * 64 + l];
        half4 a2f = a2l[nf * 64 + l];
        #pragma unroll
        for (int tt = 0; tt < 8; ++tt) {
            float4v d = __builtin_amdgcn_mfma_f32_16x16x16f16(a1f, bz[tt], zero4, 0, 0, 0);
            half2v p0 = __builtin_amdgcn_cvt_pkrtz(d.x, d.y);
            half2v p1 = __builtin_amdgcn_cvt_pkrtz(d.z, d.w);
            half4 bu; bu.x = p0.x; bu.y = p0.y; bu.z = p1.x; bu.w = p1.y;
            bu = __builtin_elementwise_max(bu, zh);
            acc[tt] = __builtin_amdgcn_mfma_f32_16x16x16f16(a2f, bu, acc[tt], 0, 0, 0);
        }
    }

    // ---- epilogue: residual + LN2 + store (lanes 0-31, 8 tiles) ----
    if (l < 32) {
        const float4 lb4 = *reinterpret_cast<const float4*>(&wl[O_L2B + kg]);
        const float4 g4  = *reinterpret_cast<const float4*>(&wl[O_G2 + kg]);
        const float4 bb4 = *reinterpret_cast<const float4*>(&wl[O_B2 + kg]);

        #pragma unroll
        for (int tt = 0; tt < 8; ++tt) {
            const int ltok = (tt & 4) * 64 + wtok + (tt & 3) * 16 + m;
            float4 h4 = *reinterpret_cast<const float4*>(&lds_hh[ltok][kg]);
            float r2[4];
            r2[0] = h4.x + acc[tt].x + lb4.x;
            r2[1] = h4.y + acc[tt].y + lb4.y;
            r2[2] = h4.z + acc[tt].z + lb4.z;
            r2[3] = h4.w + acc[tt].w + lb4.w;
            float part = ((r2[0] + r2[1]) + (r2[2] + r2[3]));
            float mean2 = (part + SWZ16(part)) * 0.125f;
            float d0 = r2[0] - mean2, d1_ = r2[1] - mean2,
                  d2 = r2[2] - mean2, d3 = r2[3] - mean2;
            float vp = ((d0 * d0 + d1_ * d1_) + (d2 * d2 + d3 * d3));
            float rs2 = __builtin_amdgcn_rsqf((vp + SWZ16(vp)) * 0.125f + 1e-5f);
            float4 o;
            o.x = fmaf(d0 * rs2, g4.x, bb4.x);
            o.y = fmaf(d1_ * rs2, g4.y, bb4.y);
            o.z = fmaf(d2 * rs2, g4.z, bb4.z);
            o.w = fmaf(d3 * rs2, g4.w, bb4.w);
            *reinterpret_cast<float4*>(out + (gbase + ltok) * 8 + kg) = o;
        }
    }
}

extern "C" void kernel_launch(void* const* d_in, const int* in_sizes, int n_in,
                              void* d_out, int out_size, void* d_ws, size_t ws_size,
                              hipStream_t stream) {
    const float* x   = (const float*)d_in[0];
    const float* ipw = (const float*)d_in[1];
    const float* ipb = (const float*)d_in[2];
    const float* opw = (const float*)d_in[3];
    const float* opb = (const float*)d_in[4];
    const float* rxa = (const float*)d_in[5];
    const float* cw  = (const float*)d_in[6];
    const float* cb  = (const float*)d_in[7];
    const float* g1  = (const float*)d_in[8];
    const float* b1  = (const float*)d_in[9];
    const float* rxf = (const float*)d_in[10];
    const float* l1w = (const float*)d_in[11];
    const float* l1b = (const float*)d_in[12];
    const float* l2w = (const float*)d_in[13];
    const float* l2b = (const float*)d_in[14];
    const float* g2  = (const float*)d_in[15];
    const float* b2  = (const float*)d_in[16];
    float* out = (float*)d_out;

    const int tokens = 16384 * 8;               // 131072
    tbq_fused<<<dim3(tokens / 512), dim3(256), 0, stream>>>(
        x, ipw, ipb, opw, opb, rxa, cw, cb, g1, b1, rxf,
        l1w, l1b, l2w, l2b, g2, b2, out);
}